// Round 1
// baseline (20.025 us; speedup 1.0000x reference)
//
#include <hip/hip_runtime.h>
#include <math.h>

#define NB    2048
#define FEAT  10
#define IN_DIM 7
#define HID   64
#define TAU   22
#define ALPHA 0.2f

// One block per batch item. Threads 0..127 handle half "u" (nodes 0..127),
// threads 128..255 handle half "d" (nodes 128..255 of fp).
// Star-graph GAT collapses to:
//   g_half = (elu(x0 @ W1) + 127*elu((att^T x) @ W1)) @ W2
// where att = softmax_{m=1..127}(leakyrelu(x0.ws1 + x[m].ws2)),
//       ws1 = W1 @ a[:64], ws2 = W1 @ a[64:].
// Layer-2 attention params are mathematically unused (uniform softmax).
__global__ __launch_bounds__(256) void gat_star_fused(
    const float* __restrict__ fp,
    const float* __restrict__ uW1, const float* __restrict__ uA1,
    const float* __restrict__ uW2,
    const float* __restrict__ dW1, const float* __restrict__ dA1,
    const float* __restrict__ dW2,
    const float* __restrict__ fcW, const float* __restrict__ fcB,
    float* __restrict__ out)
{
    __shared__ float xs[256 * FEAT];       // staged fp[b]  (10 KB)
    __shared__ float ws1[2][IN_DIM];       // W1 @ a_lo per half
    __shared__ float ws2[2][IN_DIM];       // W1 @ a_hi per half
    __shared__ float red[2][4];            // per-wave max / sum partials
    __shared__ float red_xa[4][IN_DIM];    // per-wave xa partials
    __shared__ float xa[2][IN_DIM];        // attention-weighted feature sum
    __shared__ float vvec[2][HID];         // elu(h1_1) + 127*elu(h1_0)
    __shared__ float tot[HID];             // g_u + g_d

    const int tid  = threadIdx.x;
    const int b    = blockIdx.x;
    const int half = tid >> 7;             // 0 = u, 1 = d
    const int m    = tid & 127;            // node within half
    const int wave = tid >> 6;             // 0..3

    // ---- Phase A: stage fp[b] (2560 floats) into LDS, coalesced float4 ----
    {
        const float4* src = (const float4*)(fp + (size_t)b * 256 * FEAT);
        float4* dst = (float4*)xs;
        #pragma unroll
        for (int i = 0; i < 3; ++i) {
            int idx = tid + i * 256;
            if (idx < 256 * FEAT / 4) dst[idx] = src[idx];
        }
    }

    // ---- Phase B: ws1/ws2 = W1 @ a  (4 tasks x 7 feats, 64 MACs each) ----
    if (tid < 28) {
        int f     = tid % IN_DIM;
        int which = tid / IN_DIM;          // 0:u-s1 1:u-s2 2:d-s1 3:d-s2
        const float* W1 = (which < 2) ? uW1 : dW1;
        const float* A1 = (which < 2) ? uA1 : dA1;
        const float* a  = A1 + ((which & 1) ? HID : 0);
        float s = 0.f;
        for (int k = 0; k < HID; ++k) s += W1[f * HID + k] * a[k];
        if (which & 1) ws2[which >> 1][f] = s;
        else           ws1[which >> 1][f] = s;
    }
    __syncthreads();

    // ---- Phase C: attention logits e[m] = leakyrelu(s1 + s2[m]) ----
    float e;
    {
        const float* x0 = xs + half * 128 * FEAT;  // node 0 of this half
        const float* xm = xs + tid * FEAT;         // my node
        float s1 = 0.f, s2 = 0.f;
        #pragma unroll
        for (int f = 0; f < IN_DIM; ++f) {
            s1 += x0[f] * ws1[half][f];
            s2 += xm[f] * ws2[half][f];
        }
        e = s1 + s2;
        e = (e >= 0.f) ? e : ALPHA * e;
        if (m == 0) e = -9.0e15f;                  // node 0 excluded (no self edge)
    }

    // ---- Phase D: softmax over m=1..127 within each half (2 waves) ----
    float mx = e;
    #pragma unroll
    for (int o = 32; o; o >>= 1) mx = fmaxf(mx, __shfl_xor(mx, o));
    if ((tid & 63) == 0) red[0][wave] = mx;
    __syncthreads();
    mx = fmaxf(red[0][half * 2], red[0][half * 2 + 1]);

    float p = (m == 0) ? 0.f : expf(e - mx);
    float sm = p;
    #pragma unroll
    for (int o = 32; o; o >>= 1) sm += __shfl_xor(sm, o);
    if ((tid & 63) == 0) red[1][wave] = sm;
    __syncthreads();
    sm = red[1][half * 2] + red[1][half * 2 + 1];
    const float att = p / sm;

    // ---- Phase E: xa[f] = sum_m att[m] * x[m][f]  (7 shuffle-reduces) ----
    {
        const float* xm = xs + tid * FEAT;
        #pragma unroll
        for (int f = 0; f < IN_DIM; ++f) {
            float v = att * xm[f];
            #pragma unroll
            for (int o = 32; o; o >>= 1) v += __shfl_xor(v, o);
            if ((tid & 63) == 0) red_xa[wave][f] = v;
        }
    }
    __syncthreads();
    if (tid < 2 * IN_DIM) {
        int h = tid / IN_DIM, f = tid % IN_DIM;
        xa[h][f] = red_xa[h * 2][f] + red_xa[h * 2 + 1][f];
    }
    __syncthreads();

    // ---- Phase F: v[k] = elu(x0@W1)[k] + 127*elu(xa@W1)[k] ----
    if (tid < 128) {
        int h = tid >> 6, k = tid & 63;
        const float* W1 = h ? dW1 : uW1;
        const float* x0 = xs + h * 128 * FEAT;
        float h0 = 0.f, h1 = 0.f;
        #pragma unroll
        for (int f = 0; f < IN_DIM; ++f) {
            float w = W1[f * HID + k];
            h0 += xa[h][f] * w;
            h1 += x0[f]    * w;
        }
        h0 = (h0 > 0.f) ? h0 : expm1f(h0);   // elu
        h1 = (h1 > 0.f) ? h1 : expm1f(h1);
        vvec[h][k] = h1 + 127.f * h0;
    }
    __syncthreads();

    // ---- Phase G: tot[j] = v_u @ uW2 + v_d @ dW2 ----
    if (tid < HID) {
        const int j = tid;
        float s = 0.f;
        #pragma unroll 8
        for (int k = 0; k < HID; ++k) s += vvec[0][k] * uW2[k * HID + j];
        #pragma unroll 8
        for (int k = 0; k < HID; ++k) s += vvec[1][k] * dW2[k * HID + j];
        tot[j] = s;
    }
    __syncthreads();

    // ---- Phase H: out = clip(relu(tot @ fc2_W + fc2_b), 0, 10) ----
    if (tid < TAU) {
        float s = fcB[tid];
        #pragma unroll 8
        for (int j = 0; j < HID; ++j) s += tot[j] * fcW[j * TAU + tid];
        s = fmaxf(s, 0.f);
        s = fminf(s, 10.f);
        out[(size_t)b * TAU + tid] = s;
    }
}

extern "C" void kernel_launch(void* const* d_in, const int* in_sizes, int n_in,
                              void* d_out, int out_size, void* d_ws, size_t ws_size,
                              hipStream_t stream) {
    const float* fp  = (const float*)d_in[0];
    const float* uW1 = (const float*)d_in[1];
    const float* uA1 = (const float*)d_in[2];
    const float* uW2 = (const float*)d_in[3];
    // d_in[4] = u_out_a : mathematically unused (uniform softmax in layer 2)
    const float* dW1 = (const float*)d_in[5];
    const float* dA1 = (const float*)d_in[6];
    const float* dW2 = (const float*)d_in[7];
    // d_in[8] = d_out_a : unused
    const float* fcW = (const float*)d_in[9];
    const float* fcB = (const float*)d_in[10];
    float* out = (float*)d_out;

    gat_star_fused<<<NB, 256, 0, stream>>>(fp, uW1, uA1, uW2, dW1, dA1, dW2,
                                           fcW, fcB, out);
}